// Round 1
// baseline (541.545 us; speedup 1.0000x reference)
//
#include <hip/hip_runtime.h>
#include <hip/hip_bf16.h>
#include <cstdint>
#include <cstddef>

typedef __bf16 bf16;
typedef bf16 bf16x8 __attribute__((ext_vector_type(8)));
typedef bf16 bf16x4 __attribute__((ext_vector_type(4)));
typedef float floatx4 __attribute__((ext_vector_type(4)));

#define DEVI __device__ __forceinline__

#define C_  512
#define HW_ 4096
#define B_  2
#define M_  8192   // B_*HW_

DEVI floatx4 mfma16(bf16x8 a, bf16x8 b, floatx4 c) {
  return __builtin_amdgcn_mfma_f32_16x16x32_bf16(a, b, c, 0, 0, 0);
}

// ---------------- GroupNorm stats: one block per (b,g), 32 groups of 16 ch ---
__global__ __launch_bounds__(256) void gn_stats(const float* __restrict__ x,
                                                float* __restrict__ stats) {
  int bg = blockIdx.x;          // b*32+g
  int b = bg >> 5, g = bg & 31;
  int tid = threadIdx.x;
  int c = (g << 4) + (tid & 15);
  int p0 = tid >> 4;            // 0..15
  const float* px = x + (size_t)b * HW_ * C_ + c;
  float s1 = 0.f, s2 = 0.f;
  for (int p = p0; p < HW_; p += 16) {
    float v = px[(size_t)p * C_];
    s1 += v; s2 += v * v;
  }
  for (int off = 32; off; off >>= 1) {
    s1 += __shfl_down(s1, off);
    s2 += __shfl_down(s2, off);
  }
  __shared__ float r1[4], r2[4];
  int wid = tid >> 6;
  if ((tid & 63) == 0) { r1[wid] = s1; r2[wid] = s2; }
  __syncthreads();
  if (tid == 0) {
    s1 = r1[0] + r1[1] + r1[2] + r1[3];
    s2 = r2[0] + r2[1] + r2[2] + r2[3];
    float inv = 1.0f / (HW_ * 16);
    float mean = s1 * inv;
    float var  = s2 * inv - mean * mean;
    stats[bg]      = mean;
    stats[64 + bg] = rsqrtf(var + 1e-5f);
  }
}

// ---------------- Apply GN -> h bf16 (M_ x C_) ------------------------------
__global__ __launch_bounds__(256) void gn_apply(const float* __restrict__ x,
                                                const float* __restrict__ gamma,
                                                const float* __restrict__ beta,
                                                const float* __restrict__ stats,
                                                bf16* __restrict__ h) {
  int idx = blockIdx.x * 256 + threadIdx.x;    // 4 elems each
  int m  = idx >> 7;
  int c4 = (idx & 127) << 2;
  int b = m >> 12;
  int g = c4 >> 4;
  float mean = stats[(b << 5) + g];
  float rs   = stats[64 + (b << 5) + g];
  const float4 xv = *reinterpret_cast<const float4*>(x + (size_t)m * C_ + c4);
  const float4 gv = *reinterpret_cast<const float4*>(gamma + c4);
  const float4 bv = *reinterpret_cast<const float4*>(beta + c4);
  bf16x4 o;
  o.x = (bf16)((xv.x - mean) * rs * gv.x + bv.x);
  o.y = (bf16)((xv.y - mean) * rs * gv.y + bv.y);
  o.z = (bf16)((xv.z - mean) * rs * gv.z + bv.z);
  o.w = (bf16)((xv.w - mean) * rs * gv.w + bv.w);
  *reinterpret_cast<bf16x4*>(h + (size_t)m * C_ + c4) = o;
}

// ---------------- Transpose + cast weights: wt[z][n][k] = w_z[k][n] ---------
__global__ __launch_bounds__(256) void wtrans(const float* __restrict__ wq,
                                              const float* __restrict__ wk,
                                              const float* __restrict__ wv,
                                              const float* __restrict__ wp,
                                              bf16* __restrict__ wt) {
  int z = blockIdx.z;
  const float* w = (z == 0) ? wq : (z == 1) ? wk : (z == 2) ? wv : wp;
  bf16* dst = wt + (size_t)z * C_ * C_;
  __shared__ float t[32][33];
  int k0 = blockIdx.x * 32, n0 = blockIdx.y * 32;
  int r = threadIdx.x >> 5, cc = threadIdx.x & 31;
  for (int i = 0; i < 4; i++) {
    int rr = r + i * 8;
    t[rr][cc] = w[(size_t)(k0 + rr) * C_ + n0 + cc];
  }
  __syncthreads();
  for (int i = 0; i < 4; i++) {
    int rr = r + i * 8;
    dst[(size_t)(n0 + rr) * C_ + k0 + cc] = (bf16)t[cc][rr];
  }
}

// ---------------- GEMM mainloop: C(128x64) = A(M x 512) * Bt(N x 512)^T -----
// block 256 = 4 waves; wave w: rows [w*32, w*32+32), all 64 cols.
// A-frag layout: A[m=lane&15][k=quad*8+j]; C/D: col=lane&15, row=quad*4+reg.
#define GBM 128
#define GBN 64
#define GBK 64

DEVI void gemm_main(const bf16* __restrict__ A, const bf16* __restrict__ Bt,
                    int m0, int n0, floatx4 (&acc)[2][4]) {
  __shared__ __align__(16) bf16 As[GBM][72];   // stride 72: 2-way banks (free)
  __shared__ __align__(16) bf16 Bs[GBN][72];
  int tid = threadIdx.x;
  int w = tid >> 6, lane = tid & 63;
  int col = lane & 15, quad = lane >> 4;
  for (int mt = 0; mt < 2; mt++)
    for (int nt = 0; nt < 4; nt++)
      acc[mt][nt] = floatx4{0.f, 0.f, 0.f, 0.f};
  for (int k0 = 0; k0 < C_; k0 += GBK) {
    __syncthreads();
#pragma unroll
    for (int i = 0; i < 4; i++) {            // A: 128x64 bf16, 16B/thread x4
      int id = tid + i * 256;
      int row = id >> 3, cc = id & 7;
      *reinterpret_cast<uint4*>(&As[row][cc * 8]) =
          *reinterpret_cast<const uint4*>(A + (size_t)(m0 + row) * C_ + k0 + cc * 8);
    }
#pragma unroll
    for (int i = 0; i < 2; i++) {            // B: 64x64
      int id = tid + i * 256;
      int row = id >> 3, cc = id & 7;
      *reinterpret_cast<uint4*>(&Bs[row][cc * 8]) =
          *reinterpret_cast<const uint4*>(Bt + (size_t)(n0 + row) * C_ + k0 + cc * 8);
    }
    __syncthreads();
#pragma unroll
    for (int kk = 0; kk < 2; kk++) {
      bf16x8 af[2], bf[4];
#pragma unroll
      for (int mt = 0; mt < 2; mt++)
        af[mt] = *reinterpret_cast<const bf16x8*>(&As[w * 32 + mt * 16 + col][kk * 32 + quad * 8]);
#pragma unroll
      for (int nt = 0; nt < 4; nt++)
        bf[nt] = *reinterpret_cast<const bf16x8*>(&Bs[nt * 16 + col][kk * 32 + quad * 8]);
#pragma unroll
      for (int mt = 0; mt < 2; mt++)
#pragma unroll
        for (int nt = 0; nt < 4; nt++)
          acc[mt][nt] = mfma16(af[mt], bf[nt], acc[mt][nt]);
    }
  }
}

// ---------------- QKV GEMM: z=0 -> q, z=1 -> k, z=2 -> v (transposed) -------
__global__ __launch_bounds__(256) void gemm_qkv(const bf16* __restrict__ h,
                                                const bf16* __restrict__ wt,
                                                const float* __restrict__ bq,
                                                const float* __restrict__ bk,
                                                const float* __restrict__ bv,
                                                bf16* __restrict__ q,
                                                bf16* __restrict__ k,
                                                bf16* __restrict__ vt) {
  int z = blockIdx.z;
  int m0 = blockIdx.x * GBM, n0 = blockIdx.y * GBN;
  floatx4 acc[2][4];
  gemm_main(h, wt + (size_t)z * C_ * C_, m0, n0, acc);
  int tid = threadIdx.x, w = tid >> 6, lane = tid & 63;
  int col = lane & 15, quad = lane >> 4;
  const float* bias = (z == 0) ? bq : (z == 1) ? bk : bv;
  if (z < 2) {
    bf16* out = (z == 0) ? q : k;
#pragma unroll
    for (int mt = 0; mt < 2; mt++)
#pragma unroll
      for (int nt = 0; nt < 4; nt++) {
        int n = n0 + nt * 16 + col;
        float bb = bias[n];
#pragma unroll
        for (int r = 0; r < 4; r++) {
          int m = m0 + w * 32 + mt * 16 + quad * 4 + r;
          out[(size_t)m * C_ + n] = (bf16)(acc[mt][nt][r] + bb);
        }
      }
  } else {
    // vt[b][c][s] = v[b*4096+s][c]
#pragma unroll
    for (int mt = 0; mt < 2; mt++)
#pragma unroll
      for (int nt = 0; nt < 4; nt++) {
        int n = n0 + nt * 16 + col;
        float bb = bias[n];
        int mbase = m0 + w * 32 + mt * 16 + quad * 4;
        int b = mbase >> 12;
        int s = mbase & 4095;
        bf16x4 v4;
        v4.x = (bf16)(acc[mt][nt][0] + bb);
        v4.y = (bf16)(acc[mt][nt][1] + bb);
        v4.z = (bf16)(acc[mt][nt][2] + bb);
        v4.w = (bf16)(acc[mt][nt][3] + bb);
        *reinterpret_cast<bf16x4*>(vt + (size_t)b * C_ * HW_ + (size_t)n * HW_ + s) = v4;
      }
  }
}

// ---------------- Proj GEMM + residual: out = x + o*wp + bp (fp32) ----------
__global__ __launch_bounds__(256) void gemm_proj(const bf16* __restrict__ o,
                                                 const bf16* __restrict__ wtp,
                                                 const float* __restrict__ bp,
                                                 const float* __restrict__ x,
                                                 float* __restrict__ out) {
  int m0 = blockIdx.x * GBM, n0 = blockIdx.y * GBN;
  floatx4 acc[2][4];
  gemm_main(o, wtp, m0, n0, acc);
  int tid = threadIdx.x, w = tid >> 6, lane = tid & 63;
  int col = lane & 15, quad = lane >> 4;
#pragma unroll
  for (int mt = 0; mt < 2; mt++)
#pragma unroll
    for (int nt = 0; nt < 4; nt++) {
      int n = n0 + nt * 16 + col;
      float bb = bp[n];
#pragma unroll
      for (int r = 0; r < 4; r++) {
        int m = m0 + w * 32 + mt * 16 + quad * 4 + r;
        out[(size_t)m * C_ + n] = x[(size_t)m * C_ + n] + acc[mt][nt][r] + bb;
      }
    }
}

// ---------------- Flash attention: BM=32 q rows/block, BN=64 kv tile --------
// wave w: S cols [w*16,w*16+16); O cols [w*128,(w+1)*128).
#define FBM 32
#define FBN 64
__global__ __launch_bounds__(256) void flash(const bf16* __restrict__ q,
                                             const bf16* __restrict__ k,
                                             const bf16* __restrict__ vt,
                                             bf16* __restrict__ o) {
  int b  = blockIdx.y;
  int i0 = blockIdx.x * FBM;
  int tid = threadIdx.x, w = tid >> 6, lane = tid & 63;
  int col = lane & 15, quad = lane >> 4;
  __shared__ __align__(16) bf16 Qs[FBM][520];   // stride 520: 2-way banks
  __shared__ __align__(16) bf16 Ps[FBM][72];
  __shared__ float sm[FBM], sl[FBM], salpha[FBM];
  __shared__ float wmax[4][FBM], wsum[4][FBM];
  const bf16* qb = q  + (size_t)b * HW_ * C_;
  const bf16* kb = k  + (size_t)b * HW_ * C_;
  const bf16* vb = vt + (size_t)b * C_ * HW_;
#pragma unroll
  for (int i = 0; i < 8; i++) {                 // Q tile 32x512 -> LDS
    int id = tid + i * 256;
    int row = id >> 6, cc = id & 63;
    *reinterpret_cast<uint4*>(&Qs[row][cc * 8]) =
        *reinterpret_cast<const uint4*>(qb + (size_t)(i0 + row) * C_ + cc * 8);
  }
  if (tid < FBM) { sm[tid] = -1e30f; sl[tid] = 0.f; }
  floatx4 oacc[2][8];
#pragma unroll
  for (int mt = 0; mt < 2; mt++)
#pragma unroll
    for (int nt = 0; nt < 8; nt++)
      oacc[mt][nt] = floatx4{0.f, 0.f, 0.f, 0.f};
  __syncthreads();

  const float scale = 0.044194173824159216f;    // 512^-0.5

  for (int jt = 0; jt < HW_ / FBN; jt++) {
    int j0 = jt * FBN + w * 16;
    // ---- S = Q K^T (this wave: 32 rows x its 16 cols) ----
    floatx4 sacc[2] = {floatx4{0.f,0.f,0.f,0.f}, floatx4{0.f,0.f,0.f,0.f}};
#pragma unroll
    for (int d0 = 0; d0 < C_; d0 += 32) {
      bf16x8 bfr = *reinterpret_cast<const bf16x8*>(kb + (size_t)(j0 + col) * C_ + d0 + quad * 8);
#pragma unroll
      for (int mt = 0; mt < 2; mt++) {
        bf16x8 af = *reinterpret_cast<const bf16x8*>(&Qs[mt * 16 + col][d0 + quad * 8]);
        sacc[mt] = mfma16(af, bfr, sacc[mt]);
      }
    }
    float vv[2][4], mx[2][4];
#pragma unroll
    for (int mt = 0; mt < 2; mt++)
#pragma unroll
      for (int r = 0; r < 4; r++) { vv[mt][r] = sacc[mt][r] * scale; mx[mt][r] = vv[mt][r]; }
    // tile row-max over the 16 col-lanes
#pragma unroll
    for (int off = 1; off < 16; off <<= 1)
#pragma unroll
      for (int mt = 0; mt < 2; mt++)
#pragma unroll
        for (int r = 0; r < 4; r++)
          mx[mt][r] = fmaxf(mx[mt][r], __shfl_xor(mx[mt][r], off));
    if (col == 0)
#pragma unroll
      for (int mt = 0; mt < 2; mt++)
#pragma unroll
        for (int r = 0; r < 4; r++)
          wmax[w][mt * 16 + quad * 4 + r] = mx[mt][r];
    __syncthreads();                                        // A
    if (tid < FBM) {
      float t0 = fmaxf(fmaxf(wmax[0][tid], wmax[1][tid]), fmaxf(wmax[2][tid], wmax[3][tid]));
      float mo = sm[tid];
      float mn = fmaxf(mo, t0);
      sm[tid] = mn;
      salpha[tid] = __expf(mo - mn);
    }
    __syncthreads();                                        // B
    // ---- P = exp(S - m), rescale O, row sums ----
    float pf[2][4];
#pragma unroll
    for (int mt = 0; mt < 2; mt++) {
#pragma unroll
      for (int r = 0; r < 4; r++) {
        int row = mt * 16 + quad * 4 + r;
        float al = salpha[row];
#pragma unroll
        for (int nt = 0; nt < 8; nt++) oacc[mt][nt][r] *= al;
        float p = __expf(vv[mt][r] - sm[row]);
        bf16 pb = (bf16)p;
        Ps[row][w * 16 + col] = pb;
        pf[mt][r] = (float)pb;   // sum the ROUNDED p so l matches PV exactly
      }
    }
#pragma unroll
    for (int off = 1; off < 16; off <<= 1)
#pragma unroll
      for (int mt = 0; mt < 2; mt++)
#pragma unroll
        for (int r = 0; r < 4; r++)
          pf[mt][r] += __shfl_xor(pf[mt][r], off);
    if (col == 0)
#pragma unroll
      for (int mt = 0; mt < 2; mt++)
#pragma unroll
        for (int r = 0; r < 4; r++)
          wsum[w][mt * 16 + quad * 4 + r] = pf[mt][r];
    __syncthreads();                                        // C
    if (tid < FBM)
      sl[tid] = sl[tid] * salpha[tid] +
                (wsum[0][tid] + wsum[1][tid] + wsum[2][tid] + wsum[3][tid]);
    // ---- O += P V (this wave: 32 rows x its 128 cols) ----
#pragma unroll
    for (int kk = 0; kk < 2; kk++) {
      bf16x8 af[2];
#pragma unroll
      for (int mt = 0; mt < 2; mt++)
        af[mt] = *reinterpret_cast<const bf16x8*>(&Ps[mt * 16 + col][kk * 32 + quad * 8]);
#pragma unroll
      for (int nt = 0; nt < 8; nt++) {
        int c = w * 128 + nt * 16 + col;
        bf16x8 bfr = *reinterpret_cast<const bf16x8*>(
            vb + (size_t)c * HW_ + jt * FBN + kk * 32 + quad * 8);
#pragma unroll
        for (int mt = 0; mt < 2; mt++)
          oacc[mt][nt] = mfma16(af[mt], bfr, oacc[mt][nt]);
      }
    }
    // next iter's barriers A/B separate these Ps reads from the next writes
  }
  __syncthreads();
  bf16* ob = o + (size_t)b * HW_ * C_;
#pragma unroll
  for (int mt = 0; mt < 2; mt++)
#pragma unroll
    for (int r = 0; r < 4; r++) {
      int row = mt * 16 + quad * 4 + r;
      float inv = 1.0f / sl[row];
#pragma unroll
      for (int nt = 0; nt < 8; nt++) {
        int c = w * 128 + nt * 16 + col;
        ob[(size_t)(i0 + row) * C_ + c] = (bf16)(oacc[mt][nt][r] * inv);
      }
    }
}

// ---------------- launch -----------------------------------------------------
extern "C" void kernel_launch(void* const* d_in, const int* in_sizes, int n_in,
                              void* d_out, int out_size, void* d_ws, size_t ws_size,
                              hipStream_t stream) {
  const float* x     = (const float*)d_in[0];
  const float* gamma = (const float*)d_in[1];
  const float* beta  = (const float*)d_in[2];
  const float* wq    = (const float*)d_in[3];
  const float* bq    = (const float*)d_in[4];
  const float* wk    = (const float*)d_in[5];
  const float* bk    = (const float*)d_in[6];
  const float* wv    = (const float*)d_in[7];
  const float* bv    = (const float*)d_in[8];
  const float* wp    = (const float*)d_in[9];
  const float* bp    = (const float*)d_in[10];
  float* out = (float*)d_out;

  char* w8 = (char*)d_ws;
  float* stats = (float*)(w8);                       // 512 B
  bf16* wt = (bf16*)(w8 + (1u << 20));               // 4*512*512*2 = 2 MB
  bf16* h  = (bf16*)(w8 + (4u << 20));               // 8 MB (reused as attn-out)
  bf16* q  = (bf16*)(w8 + 12582912u);                // 8 MB
  bf16* kk = (bf16*)(w8 + 20971520u);                // 8 MB
  bf16* vt = (bf16*)(w8 + 29360128u);                // 8 MB -> total 36 MB
  bf16* o  = h;

  gn_stats<<<64, 256, 0, stream>>>(x, stats);
  gn_apply<<<4096, 256, 0, stream>>>(x, gamma, beta, stats, h);
  wtrans<<<dim3(16, 16, 4), 256, 0, stream>>>(wq, wk, wv, wp, wt);
  gemm_qkv<<<dim3(M_ / GBM, C_ / GBN, 3), 256, 0, stream>>>(h, wt, bq, bk, bv, q, kk, vt);
  flash<<<dim3(HW_ / FBM, B_), 256, 0, stream>>>(q, kk, vt, o);
  gemm_proj<<<dim3(M_ / GBM, C_ / GBN, 1), 256, 0, stream>>>(o, wt + (size_t)3 * C_ * C_, bp, x, out);
}